// Round 1
// baseline (474.718 us; speedup 1.0000x reference)
//
#include <hip/hip_runtime.h>

#define MM 128
#define NN 128
#define KK 128
#define NBATCH 4
#define ITERS 8
#define WIN 10
#define WSTRIDE 12
#define PLANE (WIN * WSTRIDE)   // 120 floats per window plane
#define BUFSZ (WIN * PLANE)     // 1200 floats per window buffer
#define MNK (MM * NN * KK)

__device__ __forceinline__ float wave_sum(float v) {
  v += __shfl_xor(v, 32, 64);
  v += __shfl_xor(v, 16, 64);
  v += __shfl_xor(v, 8, 64);
  v += __shfl_xor(v, 4, 64);
  v += __shfl_xor(v, 2, 64);
  v += __shfl_xor(v, 1, 64);
  return v;
}

// One workgroup (512 threads = 8 waves) per 8^3 spatial block; thread t owns
// interior cell (p,q,r) = (t>>6, (t>>3)&7, t&7) for all 4 batches, with its 27
// conv weights in registers across batches+iterations (27 regs -> 8 waves/SIMD).
// Window buffers are ping-ponged so each inner iteration needs ONE barrier.
// LDS conv reads are b32 with bank index (12q+r)%32: exactly 2 lanes/bank (free).
__global__ __launch_bounds__(512, 8) void gridnet_kernel(
    const float* __restrict__ weight, const float* __restrict__ bias,
    const float* __restrict__ rscale, const float* __restrict__ x,
    float* __restrict__ out) {
  __shared__ float Wl[2][BUFSZ];
  __shared__ float red[64];   // [0,16)/[16,32): per-iter banks; [32,48+): batch stats

  const int t = threadIdx.x;
  const int r = t & 7, q = (t >> 3) & 7, p = t >> 6;
  const int wv = t >> 6;  // wave id == p-plane

  // XCD-pair swizzle: dispatch round-robins XCDs (d%8). Map so spatial blocks
  // (pair along bk, which share 64B weight/x cache lines) land on the SAME XCD
  // 8 dispatch slots apart -> second reader hits that XCD's L2, halving fetch.
  const int d = blockIdx.x;
  const int xcd = d & 7, dj = d >> 3;
  const int sp = xcd * 512 + ((dj >> 1) << 1) + (dj & 1);
  const int bm = sp >> 8, bn = (sp >> 4) & 15, bk = sp & 15;

  const int gm0 = bm * 8, gn0 = bn * 8, gk0 = bk * 8;
  const int g = ((gm0 + p) * NN + (gn0 + q)) * KK + (gk0 + r);

  // per-thread weights: w[o], o = i*9 + j*3 + k
  float w[27];
  float S = 0.f;
#pragma unroll
  for (int o = 0; o < 27; ++o) {
    w[o] = weight[o * MNK + g];
    S += w[o];
  }
  const float bia = bias[g];
  const float rsc = rscale[g];

  const int cb = p * PLANE + q * WSTRIDE + r;  // conv read base (window coords)
  const int wb = cb + PLANE + WSTRIDE + 1;     // own interior cell in window

  for (int b = 0; b < NBATCH; ++b) {
    __syncthreads();  // previous batch's last conv reads done before restaging
    // ---- stage 10^3 window (zero-padded at grid boundary) into buffer 0;
    //      halo (iteration-invariant) is mirrored into buffer 1 ----
    float sA = 0.f, sAq = 0.f, sH = 0.f, sHq = 0.f;
    for (int idx = t; idx < 1000; idx += 512) {
      int wp = idx / 100;
      int rem = idx - wp * 100;
      int wq = rem / 10;
      int wk = rem - wq * 10;
      int gm = gm0 - 1 + wp, gn = gn0 - 1 + wq, gk = gk0 - 1 + wk;
      float v = 0.f;
      if ((unsigned)gm < 128u && (unsigned)gn < 128u && (unsigned)gk < 128u)
        v = x[((b * MM + gm) * NN + gn) * KK + gk];
      int li = wp * PLANE + wq * WSTRIDE + wk;
      Wl[0][li] = v;
      sA += v; sAq += v * v;
      if (wp == 0 || wp == 9 || wq == 0 || wq == 9 || wk == 0 || wk == 9) {
        Wl[1][li] = v;
        sH += v; sHq += v * v;
      }
    }
    sA = wave_sum(sA); sAq = wave_sum(sAq);
    sH = wave_sum(sH); sHq = wave_sum(sHq);
    if ((t & 63) == 0) {
      float4 pk; pk.x = sA; pk.y = sAq; pk.z = sH; pk.w = sHq;
      *(float4*)&red[32 + wv * 4] = pk;
    }
    __syncthreads();
    float totS = 0.f, totQ = 0.f, hS = 0.f, hQ = 0.f;
#pragma unroll
    for (int i = 0; i < 8; ++i) {
      float4 pk = *(const float4*)&red[32 + i * 4];
      totS += pk.x; totQ += pk.y; hS += pk.z; hQ += pk.w;
    }
    float a = Wl[0][wb];  // own interior act, kept in register
    float mu = totS * (1.0f / 1000.0f);
    float var = totQ * (1.0f / 1000.0f) - mu * mu;
    float inv = __builtin_amdgcn_rsqf(var + 1e-5f);

    for (int it = 0; it < ITERS; ++it) {
      // ---- 3^3 locally-connected conv on RAW acts (normalization folded) ----
      const float* __restrict__ cp = &Wl[it & 1][cb];
      float acc = 0.f;
#pragma unroll
      for (int i = 0; i < 3; ++i) {
        float ai = 0.f;
#pragma unroll
        for (int jj = 0; jj < 3; ++jj) {
          const float* rp = cp + i * PLANE + jj * WSTRIDE;
          const int o = i * 9 + jj * 3;
          ai += w[o] * rp[0] + w[o + 1] * rp[1] + w[o + 2] * rp[2];
        }
        acc += ai;
      }
      // acc_final = bias + inv*conv_raw - inv*mu*(sum of 27 weights)
      float z = bia + inv * acc - (inv * mu) * S;
      float e = __expf(-z);
      float sg = __builtin_amdgcn_rcpf(1.0f + e);  // sigmoid(z)
      a += rsc * (z * sg);                         // residual silu
      if (it < ITERS - 1) {
        // write into the OTHER buffer: readers of 'cur' finished before the
        // barrier at the end of the previous iteration -> no pre-write barrier
        Wl[(it & 1) ^ 1][wb] = a;
        float ls = wave_sum(a);
        float lq = wave_sum(a * a);
        const int bank = (it & 1) * 16;  // alternate red banks: no race window
        if ((t & 63) == 0) {
          float2 pk; pk.x = ls; pk.y = lq;
          *(float2*)&red[bank + wv * 2] = pk;
        }
        __syncthreads();  // new interior visible AND partials ready
        float tS = hS, tQ = hQ;
#pragma unroll
        for (int i = 0; i < 8; ++i) {
          float2 pk = *(const float2*)&red[bank + i * 2];
          tS += pk.x; tQ += pk.y;
        }
        mu = tS * (1.0f / 1000.0f);
        var = tQ * (1.0f / 1000.0f) - mu * mu;
        inv = __builtin_amdgcn_rsqf(var + 1e-5f);
      }
    }
    // ---- final interior from register ----
    out[b * MNK + g] = a;
  }
}

extern "C" void kernel_launch(void* const* d_in, const int* in_sizes, int n_in,
                              void* d_out, int out_size, void* d_ws, size_t ws_size,
                              hipStream_t stream) {
  const float* weight = (const float*)d_in[0];
  const float* bias   = (const float*)d_in[1];
  const float* rscale = (const float*)d_in[2];
  const float* x      = (const float*)d_in[3];
  // d_in[4] = inner_iterations (8), d_in[5] = block_size (8): fixed by harness
  float* out = (float*)d_out;
  gridnet_kernel<<<dim3(16 * 16 * 16), dim3(512), 0, stream>>>(
      weight, bias, rscale, x, out);
}

// Round 2
// 420.367 us; speedup vs baseline: 1.1293x; 1.1293x over previous
//
#include <hip/hip_runtime.h>

#define MM 128
#define NN 128
#define KK 128
#define NBATCH 4
#define ITERS 8
#define WIN 10
#define WSTRIDE 12
#define PLANE (WIN * WSTRIDE)   // 120 floats per window plane
#define BUFSZ (WIN * PLANE)     // 1200 floats per window buffer
#define MNK (MM * NN * KK)

__device__ __forceinline__ float wave_sum(float v) {
  v += __shfl_xor(v, 32, 64);
  v += __shfl_xor(v, 16, 64);
  v += __shfl_xor(v, 8, 64);
  v += __shfl_xor(v, 4, 64);
  v += __shfl_xor(v, 2, 64);
  v += __shfl_xor(v, 1, 64);
  return v;
}

// One workgroup (512 threads = 8 waves) per 8^3 spatial block; thread t owns
// interior cell (p,q,r) = (t>>6, (t>>3)&7, t&7) for all 4 batches, with its 27
// conv weights in registers across batches+iterations.
// launch_bounds(512,6): ~80-VGPR budget. (512,8)'s 64-VGPR budget made the
// compiler spill w[27] wholesale (VGPR_Count=32, WRITE_SIZE 115MB of scratch)
// -> 475us. The weights MUST stay in registers.
// Window buffers are ping-ponged so each inner iteration needs ONE barrier.
// LDS conv reads are b32 with bank index (12q+r)%32: exactly 2 lanes/bank (free).
__global__ __launch_bounds__(512, 6) void gridnet_kernel(
    const float* __restrict__ weight, const float* __restrict__ bias,
    const float* __restrict__ rscale, const float* __restrict__ x,
    float* __restrict__ out) {
  __shared__ float Wl[2][BUFSZ];
  __shared__ float red[64];   // [0,16)/[16,32): per-iter banks; [32,64): batch stats

  const int t = threadIdx.x;
  const int r = t & 7, q = (t >> 3) & 7, p = t >> 6;
  const int wv = t >> 6;  // wave id == p-plane

  // XCD-pair swizzle: dispatch round-robins XCDs (d%8). Map so spatial blocks
  // adjacent along bk (which share 64B weight/x cache lines) land on the SAME
  // XCD -> second reader hits that XCD's L2. (Cut FETCH 575->192MB in R1.)
  const int d = blockIdx.x;
  const int xcd = d & 7, dj = d >> 3;
  const int sp = xcd * 512 + dj;
  const int bm = sp >> 8, bn = (sp >> 4) & 15, bk = sp & 15;

  const int gm0 = bm * 8, gn0 = bn * 8, gk0 = bk * 8;
  const int g = ((gm0 + p) * NN + (gn0 + q)) * KK + (gk0 + r);

  // per-thread weights: w[o], o = i*9 + j*3 + k
  float w[27];
  float S = 0.f;
#pragma unroll
  for (int o = 0; o < 27; ++o) {
    w[o] = weight[o * MNK + g];
    S += w[o];
  }
  const float bia = bias[g];
  const float rsc = rscale[g];

  const int cb = p * PLANE + q * WSTRIDE + r;  // conv read base (window coords)
  const int wb = cb + PLANE + WSTRIDE + 1;     // own interior cell in window

  for (int b = 0; b < NBATCH; ++b) {
    __syncthreads();  // previous batch's last conv reads done before restaging
    // ---- stage 10^3 window (zero-padded at grid boundary) into buffer 0;
    //      halo (iteration-invariant) is mirrored into buffer 1 ----
    float sA = 0.f, sAq = 0.f, sH = 0.f, sHq = 0.f;
    for (int idx = t; idx < 1000; idx += 512) {
      int wp = idx / 100;
      int rem = idx - wp * 100;
      int wq = rem / 10;
      int wk = rem - wq * 10;
      int gm = gm0 - 1 + wp, gn = gn0 - 1 + wq, gk = gk0 - 1 + wk;
      float v = 0.f;
      if ((unsigned)gm < 128u && (unsigned)gn < 128u && (unsigned)gk < 128u)
        v = x[((b * MM + gm) * NN + gn) * KK + gk];
      int li = wp * PLANE + wq * WSTRIDE + wk;
      Wl[0][li] = v;
      sA += v; sAq += v * v;
      if (wp == 0 || wp == 9 || wq == 0 || wq == 9 || wk == 0 || wk == 9) {
        Wl[1][li] = v;
        sH += v; sHq += v * v;
      }
    }
    sA = wave_sum(sA); sAq = wave_sum(sAq);
    sH = wave_sum(sH); sHq = wave_sum(sHq);
    if ((t & 63) == 0) {
      float4 pk; pk.x = sA; pk.y = sAq; pk.z = sH; pk.w = sHq;
      *(float4*)&red[32 + wv * 4] = pk;
    }
    __syncthreads();
    float totS = 0.f, totQ = 0.f, hS = 0.f, hQ = 0.f;
#pragma unroll
    for (int i = 0; i < 8; ++i) {
      float4 pk = *(const float4*)&red[32 + i * 4];
      totS += pk.x; totQ += pk.y; hS += pk.z; hQ += pk.w;
    }
    float a = Wl[0][wb];  // own interior act, kept in register
    float mu = totS * (1.0f / 1000.0f);
    float var = totQ * (1.0f / 1000.0f) - mu * mu;
    float inv = __builtin_amdgcn_rsqf(var + 1e-5f);

    for (int it = 0; it < ITERS; ++it) {
      // ---- 3^3 locally-connected conv on RAW acts (normalization folded) ----
      const float* __restrict__ cp = &Wl[it & 1][cb];
      float acc = 0.f;
#pragma unroll
      for (int i = 0; i < 3; ++i) {
        float ai = 0.f;
#pragma unroll
        for (int jj = 0; jj < 3; ++jj) {
          const float* rp = cp + i * PLANE + jj * WSTRIDE;
          const int o = i * 9 + jj * 3;
          ai += w[o] * rp[0] + w[o + 1] * rp[1] + w[o + 2] * rp[2];
        }
        acc += ai;
      }
      // acc_final = bias + inv*conv_raw - inv*mu*(sum of 27 weights)
      float z = bia + inv * acc - (inv * mu) * S;
      float e = __expf(-z);
      float sg = __builtin_amdgcn_rcpf(1.0f + e);  // sigmoid(z)
      a += rsc * (z * sg);                         // residual silu
      if (it < ITERS - 1) {
        // write into the OTHER buffer: readers of 'cur' finished before the
        // barrier at the end of the previous iteration -> no pre-write barrier
        Wl[(it & 1) ^ 1][wb] = a;
        float ls = wave_sum(a);
        float lq = wave_sum(a * a);
        const int bank = (it & 1) * 16;  // alternate red banks: no race window
        if ((t & 63) == 0) {
          float2 pk; pk.x = ls; pk.y = lq;
          *(float2*)&red[bank + wv * 2] = pk;
        }
        __syncthreads();  // new interior visible AND partials ready
        float tS = hS, tQ = hQ;
#pragma unroll
        for (int i = 0; i < 8; ++i) {
          float2 pk = *(const float2*)&red[bank + i * 2];
          tS += pk.x; tQ += pk.y;
        }
        mu = tS * (1.0f / 1000.0f);
        var = tQ * (1.0f / 1000.0f) - mu * mu;
        inv = __builtin_amdgcn_rsqf(var + 1e-5f);
      }
    }
    // ---- final interior from register ----
    out[b * MNK + g] = a;
  }
}

extern "C" void kernel_launch(void* const* d_in, const int* in_sizes, int n_in,
                              void* d_out, int out_size, void* d_ws, size_t ws_size,
                              hipStream_t stream) {
  const float* weight = (const float*)d_in[0];
  const float* bias   = (const float*)d_in[1];
  const float* rscale = (const float*)d_in[2];
  const float* x      = (const float*)d_in[3];
  // d_in[4] = inner_iterations (8), d_in[5] = block_size (8): fixed by harness
  float* out = (float*)d_out;
  gridnet_kernel<<<dim3(16 * 16 * 16), dim3(512), 0, stream>>>(
      weight, bias, rscale, x, out);
}

// Round 3
// 283.037 us; speedup vs baseline: 1.6772x; 1.4852x over previous
//
#include <hip/hip_runtime.h>

#define MM 128
#define NN 128
#define KK 128
#define NBATCH 4
#define ITERS 8
#define WIN 10
#define WSTRIDE 12
#define PLANE (WIN * WSTRIDE)   // 120 floats per window plane
#define BUFSZ (WIN * PLANE)     // 1200 floats per window buffer
#define MNK (MM * NN * KK)

__device__ __forceinline__ float wave_sum(float v) {
  v += __shfl_xor(v, 32, 64);
  v += __shfl_xor(v, 16, 64);
  v += __shfl_xor(v, 8, 64);
  v += __shfl_xor(v, 4, 64);
  v += __shfl_xor(v, 2, 64);
  v += __shfl_xor(v, 1, 64);
  return v;
}

// One workgroup (256 threads = 4 waves) per 8^3 spatial block. Thread t owns a
// (1,1,2) micro-tile: p = t>>5, q = (t>>2)&7, r0 = 2*(t&3), cells (p,q,r0) and
// (p,q,r0+1), for all 4 batches. 2x27 conv weights live in registers
// (54 regs; ~100 total -> 4 waves/SIMD at the 128-reg budget of (256,4)).
// This is the middle point of the weights-vs-LDS-sharing trade:
//   1 cell/thread: 27 w-regs but 108 B/cell-iter LDS  (R2: slow, spilled)
//   4 cells/thread: 108 w-regs -> 2 waves/SIMD        (R0: 270us, latency-bound)
//   2 cells/thread: 54 w-regs, 72 B/cell-iter, 4 waves/SIMD  <- this kernel
// Ping-pong window buffers: ONE barrier per inner iteration.
__global__ __launch_bounds__(256, 4) void gridnet_kernel(
    const float* __restrict__ weight, const float* __restrict__ bias,
    const float* __restrict__ rscale, const float* __restrict__ x,
    float* __restrict__ out) {
  __shared__ float Wl[2][BUFSZ];
  __shared__ float red[48];  // [0,8)/[16,24): per-iter banks; [32,48): batch stats

  const int t = threadIdx.x;
  const int r0 = (t & 3) * 2, q = (t >> 2) & 7, p = t >> 5;
  const int wv = t >> 6;

  // XCD swizzle: adjacent-bk spatial blocks (sharing 64B weight/x lines) land
  // on the same XCD -> second read hits that XCD's L2. (FETCH 575->192MB.)
  const int d = blockIdx.x;
  const int sp = (d & 7) * 512 + (d >> 3);
  const int bm = sp >> 8, bn = (sp >> 4) & 15, bk = sp & 15;

  const int gm0 = bm * 8, gn0 = bn * 8, gk0 = bk * 8;
  const int g = ((gm0 + p) * NN + (gn0 + q)) * KK + (gk0 + r0);

  // per-thread weights: w0/w1 = the two k-cells, o = i*9 + j*3 + k
  float w0[27], w1[27];
  float S0 = 0.f, S1 = 0.f;
#pragma unroll
  for (int o = 0; o < 27; ++o) {
    float2 wv2 = *(const float2*)(weight + o * MNK + g);
    w0[o] = wv2.x; w1[o] = wv2.y;
    S0 += wv2.x;   S1 += wv2.y;
  }
  const float2 bv = *(const float2*)(bias + g);
  const float2 rv = *(const float2*)(rscale + g);

  const int cb = p * PLANE + q * WSTRIDE + r0;        // conv read base
  const int wb = cb + PLANE + WSTRIDE + 1;            // own cell (r0+1 in win k)

  for (int b = 0; b < NBATCH; ++b) {
    __syncthreads();  // previous batch's last conv reads done before restaging
    // ---- stage 10^3 window (zero-padded at boundary) into buffer 0;
    //      iteration-invariant halo mirrored into buffer 1 ----
    float sA = 0.f, sAq = 0.f, sH = 0.f, sHq = 0.f;
    for (int idx = t; idx < 1000; idx += 256) {
      int wp = idx / 100;
      int rem = idx - wp * 100;
      int wq = rem / 10;
      int wk = rem - wq * 10;
      int gm = gm0 - 1 + wp, gn = gn0 - 1 + wq, gk = gk0 - 1 + wk;
      float v = 0.f;
      if ((unsigned)gm < 128u && (unsigned)gn < 128u && (unsigned)gk < 128u)
        v = x[((b * MM + gm) * NN + gn) * KK + gk];
      int li = wp * PLANE + wq * WSTRIDE + wk;
      Wl[0][li] = v;
      sA += v; sAq += v * v;
      if (wp == 0 || wp == 9 || wq == 0 || wq == 9 || wk == 0 || wk == 9) {
        Wl[1][li] = v;
        sH += v; sHq += v * v;
      }
    }
    sA = wave_sum(sA); sAq = wave_sum(sAq);
    sH = wave_sum(sH); sHq = wave_sum(sHq);
    if ((t & 63) == 0) {
      float4 pk; pk.x = sA; pk.y = sAq; pk.z = sH; pk.w = sHq;
      *(float4*)&red[32 + wv * 4] = pk;
    }
    __syncthreads();
    float totS = 0.f, totQ = 0.f, hS = 0.f, hQ = 0.f;
#pragma unroll
    for (int i = 0; i < 4; ++i) {
      float4 pk = *(const float4*)&red[32 + i * 4];
      totS += pk.x; totQ += pk.y; hS += pk.z; hQ += pk.w;
    }
    float a0 = Wl[0][wb], a1 = Wl[0][wb + 1];
    float mu = totS * (1.0f / 1000.0f);
    float var = totQ * (1.0f / 1000.0f) - mu * mu;
    float inv = __builtin_amdgcn_rsqf(var + 1e-5f);

    for (int it = 0; it < ITERS; ++it) {
      // ---- 3^3 locally-connected conv on RAW acts (normalization folded) ----
      const float* __restrict__ cp = &Wl[it & 1][cb];
      float acc0 = 0.f, acc1 = 0.f;
#pragma unroll
      for (int i = 0; i < 3; ++i) {
#pragma unroll
        for (int jj = 0; jj < 3; ++jj) {
          const float* rp = cp + i * PLANE + jj * WSTRIDE;
          float2 u0 = *(const float2*)rp;         // k: r0, r0+1
          float2 u1 = *(const float2*)(rp + 2);   // k: r0+2, r0+3
          const int o = i * 9 + jj * 3;
          acc0 += w0[o] * u0.x + w0[o + 1] * u0.y + w0[o + 2] * u1.x;
          acc1 += w1[o] * u0.y + w1[o + 1] * u1.x + w1[o + 2] * u1.y;
        }
      }
      // acc_final = bias + inv*conv_raw - inv*mu*(sum of 27 weights)
      const float im = inv * mu;
      float z0 = bv.x + inv * acc0 - im * S0;
      float z1 = bv.y + inv * acc1 - im * S1;
      float sg0 = __builtin_amdgcn_rcpf(1.0f + __expf(-z0));
      float sg1 = __builtin_amdgcn_rcpf(1.0f + __expf(-z1));
      a0 += rv.x * (z0 * sg0);
      a1 += rv.y * (z1 * sg1);
      if (it < ITERS - 1) {
        // write the OTHER buffer: iter N's readers of buf[cur] all finished
        // before iter N's barrier -> no pre-write barrier needed
        float* wp_ = &Wl[(it & 1) ^ 1][wb];
        wp_[0] = a0; wp_[1] = a1;
        float ls = wave_sum(a0 + a1);
        float lq = wave_sum(a0 * a0 + a1 * a1);
        const int bank = (it & 1) * 16;  // alternate banks: no write/read race
        if ((t & 63) == 0) {
          float2 pk; pk.x = ls; pk.y = lq;
          *(float2*)&red[bank + wv * 2] = pk;
        }
        __syncthreads();  // new interior visible AND partials ready
        float tS = hS, tQ = hQ;
#pragma unroll
        for (int i = 0; i < 4; ++i) {
          float2 pk = *(const float2*)&red[bank + i * 2];
          tS += pk.x; tQ += pk.y;
        }
        mu = tS * (1.0f / 1000.0f);
        var = tQ * (1.0f / 1000.0f) - mu * mu;
        inv = __builtin_amdgcn_rsqf(var + 1e-5f);
      }
    }
    // ---- final interior from registers (r0 even -> float2-aligned) ----
    float2 ov; ov.x = a0; ov.y = a1;
    *(float2*)(out + b * MNK + g) = ov;
  }
}

extern "C" void kernel_launch(void* const* d_in, const int* in_sizes, int n_in,
                              void* d_out, int out_size, void* d_ws, size_t ws_size,
                              hipStream_t stream) {
  const float* weight = (const float*)d_in[0];
  const float* bias   = (const float*)d_in[1];
  const float* rscale = (const float*)d_in[2];
  const float* x      = (const float*)d_in[3];
  // d_in[4] = inner_iterations (8), d_in[5] = block_size (8): fixed by harness
  float* out = (float*)d_out;
  gridnet_kernel<<<dim3(16 * 16 * 16), dim3(256), 0, stream>>>(
      weight, bias, rscale, x, out);
}

// Round 4
// 216.227 us; speedup vs baseline: 2.1955x; 1.3090x over previous
//
#include <hip/hip_runtime.h>

#define MM 128
#define NN 128
#define KK 128
#define NBATCH 4
#define ITERS 8
#define WIN 10
#define WSTRIDE 12
#define PLANE (WIN * WSTRIDE)   // wp stride: 10 wk-rows of 12
#define BUFSZ (WIN * PLANE)     // 1200 floats per window buffer
#define MNK (MM * NN * KK)

__device__ __forceinline__ float wave_sum(float v) {
  v += __shfl_xor(v, 32, 64);
  v += __shfl_xor(v, 16, 64);
  v += __shfl_xor(v, 8, 64);
  v += __shfl_xor(v, 4, 64);
  v += __shfl_xor(v, 2, 64);
  v += __shfl_xor(v, 1, 64);
  return v;
}

// One workgroup (256 threads = 4 waves) per 8^3 spatial block. Thread t owns a
// (1,1,2) micro-tile: p = t>>5, q = (t>>2)&7, r0 = 2*(t&3), for all 4 batches;
// 2x27 conv weights in registers.
// LDS window is stored TRANSPOSED: addr = wp*120 + wk*12 + wq (q innermost).
// Conv reads are then scalar b32 with bank = (24*(p+r2) + q) mod 32: the
// (p,r2) classes hit {0,8,16,24} twice each, q spans 0..7 -> EXACTLY 2
// lanes/bank per wave (the free case). The previous k-innermost layout put all
// 64 lanes on the 16 even banks (4-way, SQ_LDS_BANK_CONFLICT=5.3e7 ~ 86us/CU).
// Ping-pong window buffers: ONE barrier per inner iteration.
__global__ __launch_bounds__(256, 4) void gridnet_kernel(
    const float* __restrict__ weight, const float* __restrict__ bias,
    const float* __restrict__ rscale, const float* __restrict__ x,
    float* __restrict__ out) {
  __shared__ float Wl[2][BUFSZ];
  __shared__ float red[48];  // [0,8)/[16,24): per-iter banks; [32,48): batch stats

  const int t = threadIdx.x;
  const int r0 = (t & 3) * 2, q = (t >> 2) & 7, p = t >> 5;
  const int wv = t >> 6;

  // XCD swizzle: adjacent-bk spatial blocks (sharing 64B weight/x lines) land
  // on the same XCD -> second read hits that XCD's L2. (FETCH 575->192MB.)
  const int d = blockIdx.x;
  const int sp = (d & 7) * 512 + (d >> 3);
  const int bm = sp >> 8, bn = (sp >> 4) & 15, bk = sp & 15;

  const int gm0 = bm * 8, gn0 = bn * 8, gk0 = bk * 8;
  const int g = ((gm0 + p) * NN + (gn0 + q)) * KK + (gk0 + r0);

  // per-thread weights: w0/w1 = the two k-cells, o = i*9 + j*3 + k
  float w0[27], w1[27];
  float S0 = 0.f, S1 = 0.f;
#pragma unroll
  for (int o = 0; o < 27; ++o) {
    float2 wv2 = *(const float2*)(weight + o * MNK + g);
    w0[o] = wv2.x; w1[o] = wv2.y;
    S0 += wv2.x;   S1 += wv2.y;
  }
  const float2 bv = *(const float2*)(bias + g);
  const float2 rv = *(const float2*)(rscale + g);

  // transposed window coords: addr(wp,wk,wq) = wp*PLANE + wk*WSTRIDE + wq
  const int cb = p * PLANE + r0 * WSTRIDE + q;   // (i=0,jj=0,c=0) tap
  const int wb = cb + PLANE + WSTRIDE + 1;       // own cell dr=0; dr=1 at +WSTRIDE

  for (int b = 0; b < NBATCH; ++b) {
    __syncthreads();  // previous batch's last conv reads done before restaging
    // ---- stage 10^3 window (zero-padded at boundary) into buffer 0;
    //      iteration-invariant halo mirrored into buffer 1 ----
    float sA = 0.f, sAq = 0.f, sH = 0.f, sHq = 0.f;
    for (int idx = t; idx < 1000; idx += 256) {
      int wp = idx / 100;
      int rem = idx - wp * 100;
      int wq = rem / 10;
      int wk = rem - wq * 10;
      int gm = gm0 - 1 + wp, gn = gn0 - 1 + wq, gk = gk0 - 1 + wk;
      float v = 0.f;
      if ((unsigned)gm < 128u && (unsigned)gn < 128u && (unsigned)gk < 128u)
        v = x[((b * MM + gm) * NN + gn) * KK + gk];
      int li = wp * PLANE + wk * WSTRIDE + wq;   // transposed store
      Wl[0][li] = v;
      sA += v; sAq += v * v;
      if (wp == 0 || wp == 9 || wq == 0 || wq == 9 || wk == 0 || wk == 9) {
        Wl[1][li] = v;
        sH += v; sHq += v * v;
      }
    }
    sA = wave_sum(sA); sAq = wave_sum(sAq);
    sH = wave_sum(sH); sHq = wave_sum(sHq);
    if ((t & 63) == 0) {
      float4 pk; pk.x = sA; pk.y = sAq; pk.z = sH; pk.w = sHq;
      *(float4*)&red[32 + wv * 4] = pk;
    }
    __syncthreads();
    float totS = 0.f, totQ = 0.f, hS = 0.f, hQ = 0.f;
#pragma unroll
    for (int i = 0; i < 4; ++i) {
      float4 pk = *(const float4*)&red[32 + i * 4];
      totS += pk.x; totQ += pk.y; hS += pk.z; hQ += pk.w;
    }
    float a0 = Wl[0][wb], a1 = Wl[0][wb + WSTRIDE];
    float mu = totS * (1.0f / 1000.0f);
    float var = totQ * (1.0f / 1000.0f) - mu * mu;
    float inv = __builtin_amdgcn_rsqf(var + 1e-5f);

    for (int it = 0; it < ITERS; ++it) {
      // ---- 3^3 locally-connected conv on RAW acts (normalization folded) ----
      const float* __restrict__ cp = &Wl[it & 1][cb];
      float acc0 = 0.f, acc1 = 0.f;
#pragma unroll
      for (int i = 0; i < 3; ++i) {
#pragma unroll
        for (int jj = 0; jj < 3; ++jj) {
          const float* rp = cp + i * PLANE + jj;
          float u0 = rp[0];               // k tap r0
          float u1 = rp[WSTRIDE];         // k tap r0+1
          float u2 = rp[2 * WSTRIDE];     // k tap r0+2
          float u3 = rp[3 * WSTRIDE];     // k tap r0+3
          const int o = i * 9 + jj * 3;
          acc0 += w0[o] * u0 + w0[o + 1] * u1 + w0[o + 2] * u2;
          acc1 += w1[o] * u1 + w1[o + 1] * u2 + w1[o + 2] * u3;
        }
      }
      // acc_final = bias + inv*conv_raw - inv*mu*(sum of 27 weights)
      const float im = inv * mu;
      float z0 = bv.x + inv * acc0 - im * S0;
      float z1 = bv.y + inv * acc1 - im * S1;
      float sg0 = __builtin_amdgcn_rcpf(1.0f + __expf(-z0));
      float sg1 = __builtin_amdgcn_rcpf(1.0f + __expf(-z1));
      a0 += rv.x * (z0 * sg0);
      a1 += rv.y * (z1 * sg1);
      if (it < ITERS - 1) {
        // write the OTHER buffer: iter N's readers of buf[cur] all finished
        // before iter N's barrier -> no pre-write barrier needed
        float* wp_ = &Wl[(it & 1) ^ 1][wb];
        wp_[0] = a0; wp_[WSTRIDE] = a1;
        float ls = wave_sum(a0 + a1);
        float lq = wave_sum(a0 * a0 + a1 * a1);
        const int bank = (it & 1) * 16;  // alternate banks: no write/read race
        if ((t & 63) == 0) {
          float2 pk; pk.x = ls; pk.y = lq;
          *(float2*)&red[bank + wv * 2] = pk;
        }
        __syncthreads();  // new interior visible AND partials ready
        float tS = hS, tQ = hQ;
#pragma unroll
        for (int i = 0; i < 4; ++i) {
          float2 pk = *(const float2*)&red[bank + i * 2];
          tS += pk.x; tQ += pk.y;
        }
        mu = tS * (1.0f / 1000.0f);
        var = tQ * (1.0f / 1000.0f) - mu * mu;
        inv = __builtin_amdgcn_rsqf(var + 1e-5f);
      }
    }
    // ---- final interior from registers (r0 even -> float2-aligned) ----
    float2 ov; ov.x = a0; ov.y = a1;
    *(float2*)(out + b * MNK + g) = ov;
  }
}

extern "C" void kernel_launch(void* const* d_in, const int* in_sizes, int n_in,
                              void* d_out, int out_size, void* d_ws, size_t ws_size,
                              hipStream_t stream) {
  const float* weight = (const float*)d_in[0];
  const float* bias   = (const float*)d_in[1];
  const float* rscale = (const float*)d_in[2];
  const float* x      = (const float*)d_in[3];
  // d_in[4] = inner_iterations (8), d_in[5] = block_size (8): fixed by harness
  float* out = (float*)d_out;
  gridnet_kernel<<<dim3(16 * 16 * 16), dim3(256), 0, stream>>>(
      weight, bias, rscale, x, out);
}

// Round 5
// 206.743 us; speedup vs baseline: 2.2962x; 1.0459x over previous
//
#include <hip/hip_runtime.h>

#define MM 128
#define NN 128
#define KK 128
#define NB 4
#define ITERS 8
#define WIN 10
#define WSTRIDE 12
#define PLANE (WIN * WSTRIDE)   // wp stride: 10 wk-rows of 12
#define BUFSZ (WIN * PLANE)     // 1200 floats per window buffer
#define MNK (MM * NN * KK)

__device__ __forceinline__ float wave_sum(float v) {
  v += __shfl_xor(v, 32, 64);
  v += __shfl_xor(v, 16, 64);
  v += __shfl_xor(v, 8, 64);
  v += __shfl_xor(v, 4, 64);
  v += __shfl_xor(v, 2, 64);
  v += __shfl_xor(v, 1, 64);
  return v;
}

// One workgroup (256 threads = 4 waves) per 8^3 spatial block. Thread t owns a
// (1,1,2) micro-tile: p = t>>5, q = (t>>2)&7, r0 = 2*(t&3); 2x27 conv weights
// in registers (weights are BATCH-INVARIANT).
// ALL 4 BATCHES IN FLIGHT: windows for b=0..3 live in LDS simultaneously
// (4 x 4.8KB, single-buffered). Each inner iteration processes 4 batches
// back-to-back -> 4x independent work per barrier phase, 15 barrier phases
// total instead of 32 (R4 was latency-bound: VALU 46%, nothing saturated).
// Single-buffer + 2 barriers/iter replaces ping-pong (halo stays in place;
// interior writes never touch it).
// LDS window is TRANSPOSED: addr = wp*120 + wk*12 + wq (q innermost) -> conv
// b32 reads hit every bank exactly twice per wave (free; R4: conflicts 63x down).
__global__ __launch_bounds__(256, 4) void gridnet_kernel(
    const float* __restrict__ weight, const float* __restrict__ bias,
    const float* __restrict__ rscale, const float* __restrict__ x,
    float* __restrict__ out) {
  __shared__ float Wl[NB][BUFSZ];
  __shared__ float red[64];

  const int t = threadIdx.x;
  const int r0 = (t & 3) * 2, q = (t >> 2) & 7, p = t >> 5;
  const int wv = t >> 6;

  // XCD swizzle: adjacent-bk spatial blocks (sharing 64B weight/x lines) land
  // on the same XCD -> second read hits that XCD's L2. (FETCH 575->139MB.)
  const int d = blockIdx.x;
  const int sp = (d & 7) * 512 + (d >> 3);
  const int bm = sp >> 8, bn = (sp >> 4) & 15, bk = sp & 15;

  const int gm0 = bm * 8, gn0 = bn * 8, gk0 = bk * 8;
  const int g = ((gm0 + p) * NN + (gn0 + q)) * KK + (gk0 + r0);

  // per-thread weights: w0/w1 = the two k-cells, o = i*9 + j*3 + k
  float w0[27], w1[27];
  float S0 = 0.f, S1 = 0.f;
#pragma unroll
  for (int o = 0; o < 27; ++o) {
    float2 wv2 = *(const float2*)(weight + o * MNK + g);
    w0[o] = wv2.x; w1[o] = wv2.y;
    S0 += wv2.x;   S1 += wv2.y;
  }
  const float2 bv = *(const float2*)(bias + g);
  const float2 rv = *(const float2*)(rscale + g);

  // transposed window coords: addr(wp,wk,wq) = wp*PLANE + wk*WSTRIDE + wq
  const int cb = p * PLANE + r0 * WSTRIDE + q;   // (i=0,jj=0,k=0) tap
  const int wb = cb + PLANE + WSTRIDE + 1;       // own cell dr=0; dr=1 at +WSTRIDE

  // ---- stage all 4 batch windows (zero-padded at grid boundary) ----
  float sA[NB] = {0.f, 0.f, 0.f, 0.f}, sAq[NB] = {0.f, 0.f, 0.f, 0.f};
  float sH[NB] = {0.f, 0.f, 0.f, 0.f}, sHq[NB] = {0.f, 0.f, 0.f, 0.f};
  for (int idx = t; idx < 1000; idx += 256) {
    int wp_ = idx / 100;
    int rem = idx - wp_ * 100;
    int wq = rem / 10;
    int wk = rem - wq * 10;
    int gm = gm0 - 1 + wp_, gn = gn0 - 1 + wq, gk = gk0 - 1 + wk;
    const bool inb = (unsigned)gm < 128u && (unsigned)gn < 128u && (unsigned)gk < 128u;
    const bool halo = (wp_ == 0 || wp_ == 9 || wq == 0 || wq == 9 || wk == 0 || wk == 9);
    const int gx = (gm * NN + gn) * KK + gk;        // only used when inb
    const int li = wp_ * PLANE + wk * WSTRIDE + wq; // transposed store
#pragma unroll
    for (int b = 0; b < NB; ++b) {
      float v = 0.f;
      if (inb) v = x[b * MNK + gx];
      Wl[b][li] = v;
      sA[b] += v; sAq[b] += v * v;
      if (halo) { sH[b] += v; sHq[b] += v * v; }
    }
  }
#pragma unroll
  for (int b = 0; b < NB; ++b) {
    sA[b] = wave_sum(sA[b]);  sAq[b] = wave_sum(sAq[b]);
    sH[b] = wave_sum(sH[b]);  sHq[b] = wave_sum(sHq[b]);
  }
  if ((t & 63) == 0) {
#pragma unroll
    for (int b = 0; b < NB; ++b) {
      float4 pk; pk.x = sA[b]; pk.y = sAq[b]; pk.z = sH[b]; pk.w = sHq[b];
      *(float4*)&red[(wv * NB + b) * 4] = pk;
    }
  }
  __syncthreads();

  float invv[NB], imv[NB], hS[NB], hQ[NB];
#pragma unroll
  for (int b = 0; b < NB; ++b) {
    float tS = 0.f, tQ = 0.f, hs = 0.f, hq = 0.f;
#pragma unroll
    for (int i = 0; i < 4; ++i) {
      float4 pk = *(const float4*)&red[(i * NB + b) * 4];  // broadcast read
      tS += pk.x; tQ += pk.y; hs += pk.z; hq += pk.w;
    }
    hS[b] = hs; hQ[b] = hq;
    float mu = tS * (1.0f / 1000.0f);
    float var = tQ * (1.0f / 1000.0f) - mu * mu;
    float inv = __builtin_amdgcn_rsqf(var + 1e-5f);
    invv[b] = inv; imv[b] = inv * mu;
  }
  float a[NB][2];
#pragma unroll
  for (int b = 0; b < NB; ++b) {
    a[b][0] = Wl[b][wb];
    a[b][1] = Wl[b][wb + WSTRIDE];
  }

  for (int it = 0; it < ITERS; ++it) {
    // ---- phase A: 3^3 locally-connected conv + silu, all 4 batches ----
    // (normalization folded: z = bias + inv*conv_raw - inv*mu*S)
#pragma unroll
    for (int b = 0; b < NB; ++b) {
      const float* __restrict__ cp = &Wl[b][cb];
      float acc0 = 0.f, acc1 = 0.f;
#pragma unroll
      for (int i = 0; i < 3; ++i) {
#pragma unroll
        for (int jj = 0; jj < 3; ++jj) {
          const float* rp = cp + i * PLANE + jj;
          float u0 = rp[0];               // k tap r0-1+0
          float u1 = rp[WSTRIDE];
          float u2 = rp[2 * WSTRIDE];
          float u3 = rp[3 * WSTRIDE];
          const int o = i * 9 + jj * 3;
          acc0 += w0[o] * u0 + w0[o + 1] * u1 + w0[o + 2] * u2;
          acc1 += w1[o] * u1 + w1[o + 1] * u2 + w1[o + 2] * u3;
        }
      }
      float z0 = bv.x + invv[b] * acc0 - imv[b] * S0;
      float z1 = bv.y + invv[b] * acc1 - imv[b] * S1;
      float sg0 = __builtin_amdgcn_rcpf(1.0f + __expf(-z0));
      float sg1 = __builtin_amdgcn_rcpf(1.0f + __expf(-z1));
      a[b][0] += rv.x * (z0 * sg0);
      a[b][1] += rv.y * (z1 * sg1);
    }
    if (it == ITERS - 1) break;
    __syncthreads();  // B: all conv reads of Wl complete
    // ---- phase C: write interiors, reduce new stats (8 interleaved chains) ----
    float ls[NB], lq[NB];
#pragma unroll
    for (int b = 0; b < NB; ++b) {
      Wl[b][wb] = a[b][0];
      Wl[b][wb + WSTRIDE] = a[b][1];
      ls[b] = wave_sum(a[b][0] + a[b][1]);
      lq[b] = wave_sum(a[b][0] * a[b][0] + a[b][1] * a[b][1]);
    }
    if ((t & 63) == 0) {
#pragma unroll
      for (int b = 0; b < NB; ++b) {
        float2 pk; pk.x = ls[b]; pk.y = lq[b];
        *(float2*)&red[(wv * NB + b) * 2] = pk;
      }
    }
    __syncthreads();  // D: interior writes visible + partials ready
#pragma unroll
    for (int b = 0; b < NB; ++b) {
      float tS = hS[b], tQ = hQ[b];
#pragma unroll
      for (int i = 0; i < 4; ++i) {
        float2 pk = *(const float2*)&red[(i * NB + b) * 2];  // broadcast read
        tS += pk.x; tQ += pk.y;
      }
      float mu = tS * (1.0f / 1000.0f);
      float var = tQ * (1.0f / 1000.0f) - mu * mu;
      float inv = __builtin_amdgcn_rsqf(var + 1e-5f);
      invv[b] = inv; imv[b] = inv * mu;
    }
  }
  // ---- final interiors from registers (r0 even -> float2-aligned) ----
#pragma unroll
  for (int b = 0; b < NB; ++b) {
    float2 ov; ov.x = a[b][0]; ov.y = a[b][1];
    *(float2*)(out + b * MNK + g) = ov;
  }
}

extern "C" void kernel_launch(void* const* d_in, const int* in_sizes, int n_in,
                              void* d_out, int out_size, void* d_ws, size_t ws_size,
                              hipStream_t stream) {
  const float* weight = (const float*)d_in[0];
  const float* bias   = (const float*)d_in[1];
  const float* rscale = (const float*)d_in[2];
  const float* x      = (const float*)d_in[3];
  // d_in[4] = inner_iterations (8), d_in[5] = block_size (8): fixed by harness
  float* out = (float*)d_out;
  gridnet_kernel<<<dim3(16 * 16 * 16), dim3(256), 0, stream>>>(
      weight, bias, rscale, x, out);
}

// Round 6
// 203.946 us; speedup vs baseline: 2.3277x; 1.0137x over previous
//
#include <hip/hip_runtime.h>

#define MM 128
#define NN 128
#define KK 128
#define NB 4
#define ITERS 8
#define WIN 10
#define WSTRIDE 12
#define PLANE (WIN * WSTRIDE)   // wp stride: 10 wk-rows of 12
#define BUFSZ (WIN * PLANE)     // 1200 floats per window buffer
#define MNK (MM * NN * KK)

__device__ __forceinline__ float wave_sum(float v) {
  v += __shfl_xor(v, 32, 64);
  v += __shfl_xor(v, 16, 64);
  v += __shfl_xor(v, 8, 64);
  v += __shfl_xor(v, 4, 64);
  v += __shfl_xor(v, 2, 64);
  v += __shfl_xor(v, 1, 64);
  return v;
}

// Force a block-uniform value into an SGPR (frees VGPR pressure).
__device__ __forceinline__ float bcast_first(float v) {
  return __uint_as_float(__builtin_amdgcn_readfirstlane(__float_as_uint(v)));
}

// One workgroup (256 threads = 4 waves) per 8^3 spatial block. Thread t owns a
// (1,1,2) micro-tile: p = t>>5, q = (t>>2)&7, r0 = 2*(t&3); 2x27 conv weights
// in registers (weights are BATCH-INVARIANT). All 4 batches in flight in LDS.
// waves_per_eu(4,4): R5's (256,4) launch bound let the compiler chase 8
// waves/SIMD (LDS fits 8 blocks) and crush regs to 64 -> 11MB of spill stores
// (WRITE 44.8MB vs 33.5MB output). Pinning min=max=4 gives a 128-reg budget;
// the kernel needs ~90-100.
// Block-uniform stats (inv, inv*mu, halo sums) are forced into SGPRs via
// readfirstlane -> ~16 fewer VGPRs at the conv loop's live-range peak.
// LDS window TRANSPOSED: addr = wp*120 + wk*12 + wq -> conv b32 reads hit
// every bank exactly 2x per wave (free; R4 cut conflicts 63x).
__global__ __attribute__((amdgpu_waves_per_eu(4, 4))) __launch_bounds__(256)
void gridnet_kernel(
    const float* __restrict__ weight, const float* __restrict__ bias,
    const float* __restrict__ rscale, const float* __restrict__ x,
    float* __restrict__ out) {
  __shared__ float Wl[NB][BUFSZ];
  __shared__ float red[64];

  const int t = threadIdx.x;
  const int r0 = (t & 3) * 2, q = (t >> 2) & 7, p = t >> 5;
  const int wv = t >> 6;

  // XCD swizzle: adjacent-bk spatial blocks (sharing 64B weight/x lines) land
  // on the same XCD -> second read hits that XCD's L2. (FETCH 575->139MB.)
  const int d = blockIdx.x;
  const int sp = (d & 7) * 512 + (d >> 3);
  const int bm = sp >> 8, bn = (sp >> 4) & 15, bk = sp & 15;

  const int gm0 = bm * 8, gn0 = bn * 8, gk0 = bk * 8;
  const int g = ((gm0 + p) * NN + (gn0 + q)) * KK + (gk0 + r0);

  // per-thread weights: w0/w1 = the two k-cells, o = i*9 + j*3 + k
  float w0[27], w1[27];
  float S0 = 0.f, S1 = 0.f;
#pragma unroll
  for (int o = 0; o < 27; ++o) {
    float2 wv2 = *(const float2*)(weight + o * MNK + g);
    w0[o] = wv2.x; w1[o] = wv2.y;
    S0 += wv2.x;   S1 += wv2.y;
  }
  const float2 bv = *(const float2*)(bias + g);
  const float2 rv = *(const float2*)(rscale + g);

  // transposed window coords: addr(wp,wk,wq) = wp*PLANE + wk*WSTRIDE + wq
  const int cb = p * PLANE + r0 * WSTRIDE + q;   // (i=0,jj=0,k=0) tap
  const int wb = cb + PLANE + WSTRIDE + 1;       // own cell dr=0; dr=1 at +WSTRIDE

  // ---- stage all 4 batch windows (zero-padded at grid boundary) ----
  float sA[NB] = {0.f, 0.f, 0.f, 0.f}, sAq[NB] = {0.f, 0.f, 0.f, 0.f};
  float sH[NB] = {0.f, 0.f, 0.f, 0.f}, sHq[NB] = {0.f, 0.f, 0.f, 0.f};
  for (int idx = t; idx < 1000; idx += 256) {
    int wp_ = idx / 100;
    int rem = idx - wp_ * 100;
    int wq = rem / 10;
    int wk = rem - wq * 10;
    int gm = gm0 - 1 + wp_, gn = gn0 - 1 + wq, gk = gk0 - 1 + wk;
    const bool inb = (unsigned)gm < 128u && (unsigned)gn < 128u && (unsigned)gk < 128u;
    const bool halo = (wp_ == 0 || wp_ == 9 || wq == 0 || wq == 9 || wk == 0 || wk == 9);
    const int gx = (gm * NN + gn) * KK + gk;        // only used when inb
    const int li = wp_ * PLANE + wk * WSTRIDE + wq; // transposed store
#pragma unroll
    for (int b = 0; b < NB; ++b) {
      float v = 0.f;
      if (inb) v = x[b * MNK + gx];
      Wl[b][li] = v;
      sA[b] += v; sAq[b] += v * v;
      if (halo) { sH[b] += v; sHq[b] += v * v; }
    }
  }
#pragma unroll
  for (int b = 0; b < NB; ++b) {
    sA[b] = wave_sum(sA[b]);  sAq[b] = wave_sum(sAq[b]);
    sH[b] = wave_sum(sH[b]);  sHq[b] = wave_sum(sHq[b]);
  }
  if ((t & 63) == 0) {
#pragma unroll
    for (int b = 0; b < NB; ++b) {
      float4 pk; pk.x = sA[b]; pk.y = sAq[b]; pk.z = sH[b]; pk.w = sHq[b];
      *(float4*)&red[(wv * NB + b) * 4] = pk;
    }
  }
  __syncthreads();

  float invv[NB], imv[NB], hS[NB], hQ[NB];  // block-uniform -> SGPRs
#pragma unroll
  for (int b = 0; b < NB; ++b) {
    float tS = 0.f, tQ = 0.f, hs = 0.f, hq = 0.f;
#pragma unroll
    for (int i = 0; i < 4; ++i) {
      float4 pk = *(const float4*)&red[(i * NB + b) * 4];  // broadcast read
      tS += pk.x; tQ += pk.y; hs += pk.z; hq += pk.w;
    }
    hS[b] = bcast_first(hs); hQ[b] = bcast_first(hq);
    float mu = tS * (1.0f / 1000.0f);
    float var = tQ * (1.0f / 1000.0f) - mu * mu;
    float inv = __builtin_amdgcn_rsqf(var + 1e-5f);
    invv[b] = bcast_first(inv); imv[b] = bcast_first(inv * mu);
  }
  float a[NB][2];
#pragma unroll
  for (int b = 0; b < NB; ++b) {
    a[b][0] = Wl[b][wb];
    a[b][1] = Wl[b][wb + WSTRIDE];
  }

  for (int it = 0; it < ITERS; ++it) {
    // ---- phase A: 3^3 locally-connected conv + silu, all 4 batches ----
    // (normalization folded: z = bias + inv*conv_raw - inv*mu*S)
#pragma unroll
    for (int b = 0; b < NB; ++b) {
      const float* __restrict__ cp = &Wl[b][cb];
      float acc0 = 0.f, acc1 = 0.f;
#pragma unroll
      for (int i = 0; i < 3; ++i) {
#pragma unroll
        for (int jj = 0; jj < 3; ++jj) {
          const float* rp = cp + i * PLANE + jj;
          float u0 = rp[0];
          float u1 = rp[WSTRIDE];
          float u2 = rp[2 * WSTRIDE];
          float u3 = rp[3 * WSTRIDE];
          const int o = i * 9 + jj * 3;
          acc0 += w0[o] * u0 + w0[o + 1] * u1 + w0[o + 2] * u2;
          acc1 += w1[o] * u1 + w1[o + 1] * u2 + w1[o + 2] * u3;
        }
      }
      float z0 = bv.x + invv[b] * acc0 - imv[b] * S0;
      float z1 = bv.y + invv[b] * acc1 - imv[b] * S1;
      float sg0 = __builtin_amdgcn_rcpf(1.0f + __expf(-z0));
      float sg1 = __builtin_amdgcn_rcpf(1.0f + __expf(-z1));
      a[b][0] += rv.x * (z0 * sg0);
      a[b][1] += rv.y * (z1 * sg1);
    }
    if (it == ITERS - 1) break;
    __syncthreads();  // all conv reads of Wl complete
    // ---- phase C: write interiors, reduce new stats (8 interleaved chains) ----
    float ls[NB], lq[NB];
#pragma unroll
    for (int b = 0; b < NB; ++b) {
      Wl[b][wb] = a[b][0];
      Wl[b][wb + WSTRIDE] = a[b][1];
      ls[b] = wave_sum(a[b][0] + a[b][1]);
      lq[b] = wave_sum(a[b][0] * a[b][0] + a[b][1] * a[b][1]);
    }
    if ((t & 63) == 0) {
#pragma unroll
      for (int b = 0; b < NB; ++b) {
        float2 pk; pk.x = ls[b]; pk.y = lq[b];
        *(float2*)&red[(wv * NB + b) * 2] = pk;
      }
    }
    __syncthreads();  // interior writes visible + partials ready
#pragma unroll
    for (int b = 0; b < NB; ++b) {
      float tS = hS[b], tQ = hQ[b];
#pragma unroll
      for (int i = 0; i < 4; ++i) {
        float2 pk = *(const float2*)&red[(i * NB + b) * 2];  // broadcast read
        tS += pk.x; tQ += pk.y;
      }
      float mu = tS * (1.0f / 1000.0f);
      float var = tQ * (1.0f / 1000.0f) - mu * mu;
      float inv = __builtin_amdgcn_rsqf(var + 1e-5f);
      invv[b] = bcast_first(inv); imv[b] = bcast_first(inv * mu);
    }
  }
  // ---- final interiors from registers (r0 even -> float2-aligned) ----
#pragma unroll
  for (int b = 0; b < NB; ++b) {
    float2 ov; ov.x = a[b][0]; ov.y = a[b][1];
    *(float2*)(out + b * MNK + g) = ov;
  }
}

extern "C" void kernel_launch(void* const* d_in, const int* in_sizes, int n_in,
                              void* d_out, int out_size, void* d_ws, size_t ws_size,
                              hipStream_t stream) {
  const float* weight = (const float*)d_in[0];
  const float* bias   = (const float*)d_in[1];
  const float* rscale = (const float*)d_in[2];
  const float* x      = (const float*)d_in[3];
  // d_in[4] = inner_iterations (8), d_in[5] = block_size (8): fixed by harness
  float* out = (float*)d_out;
  gridnet_kernel<<<dim3(16 * 16 * 16), dim3(256), 0, stream>>>(
      weight, bias, rscale, x, out);
}